// Round 1
// baseline (737.085 us; speedup 1.0000x reference)
//
#include <hip/hip_runtime.h>
#include <hip/hip_bf16.h>

// ---------------- types ----------------
typedef _Float16 half8 __attribute__((ext_vector_type(8)));
typedef _Float16 half4 __attribute__((ext_vector_type(4)));
typedef float floatx4 __attribute__((ext_vector_type(4)));

#define MFMA16(a, b, c) __builtin_amdgcn_mfma_f32_16x16x32_f16(a, b, c, 0, 0, 0)

// Problem constants
#define BATCH 128
#define NTOK 197
#define DIM 768
#define NH 12
#define DH 64
#define TABLE 730
#define M_ROWS (BATCH * NTOK)       // 25216 = 197 * 128
#define KPAD 224                    // padded key count for PV (7 * 32)
#define NKT 13                      // key tiles of 16 for S (13*16 = 208 >= 197)

// ---------------- fp32 -> fp16 convert ----------------
__global__ void cvt_f32_f16(const float* __restrict__ src, _Float16* __restrict__ dst, int n4) {
    int i = blockIdx.x * 256 + threadIdx.x;
    if (i < n4) {
        float4 v = ((const float4*)src)[i];
        half4 o;
        o[0] = (_Float16)v.x; o[1] = (_Float16)v.y;
        o[2] = (_Float16)v.z; o[3] = (_Float16)v.w;
        ((half4*)dst)[i] = o;
    }
}

// ---------------- bias precompute: [12][197][224], pad cols = -1e30 ----------------
__global__ void bias_pre(const float* __restrict__ table, const int* __restrict__ ridx,
                         float* __restrict__ biasp) {
    int idx = blockIdx.x * 256 + threadIdx.x;
    if (idx >= NH * NTOK * KPAD) return;
    int h = idx / (NTOK * KPAD);
    int rem = idx - h * (NTOK * KPAD);
    int i = rem / KPAD;
    int j = rem - i * KPAD;
    float v = -1.0e30f;
    if (j < NTOK) v = table[ridx[i * NTOK + j] * NH + h];
    biasp[idx] = v;
}

// ---------------- QKV GEMM: [25216,768] x [2304,768]^T, scatter to q/k/v [B,H,N,64] f16 ----------------
// block 256 thr = 4 waves; wave computes 64x64; block 128x128. grid (2304/128=18, 25216/128=197)
__global__ __launch_bounds__(256) void qkv_gemm(const _Float16* __restrict__ X,
                                                const _Float16* __restrict__ W,
                                                _Float16* __restrict__ qh,
                                                _Float16* __restrict__ kh,
                                                _Float16* __restrict__ vh) {
    const int lane = threadIdx.x & 63;
    const int w = threadIdx.x >> 6;
    const int r = lane & 15, q = lane >> 4;
    const int m0 = blockIdx.y * 128 + (w & 1) * 64;
    const int n0 = blockIdx.x * 128 + (w >> 1) * 64;

    floatx4 acc[4][4] = {};
    const half8* pa[4];
    const half8* pb[4];
#pragma unroll
    for (int i = 0; i < 4; ++i)
        pa[i] = (const half8*)X + ((size_t)(m0 + i * 16 + r) * 96 + q);   // 768/8 = 96 half8 per row
#pragma unroll
    for (int j = 0; j < 4; ++j)
        pb[j] = (const half8*)W + ((size_t)(n0 + j * 16 + r) * 96 + q);

    for (int kk = 0; kk < 24; ++kk) {
        half8 a[4], b[4];
#pragma unroll
        for (int i = 0; i < 4; ++i) a[i] = pa[i][kk * 4];
#pragma unroll
        for (int j = 0; j < 4; ++j) b[j] = pb[j][kk * 4];
#pragma unroll
        for (int i = 0; i < 4; ++i)
#pragma unroll
            for (int j = 0; j < 4; ++j)
                acc[i][j] = MFMA16(a[i], b[j], acc[i][j]);
    }

    // epilogue: n0 is a multiple of 64, a 64-col block never crosses the 768 boundary
    const int which = n0 / 768;              // 0=q 1=k 2=v (uniform per wave)
    const int hh = (n0 % 768) / 64;
    _Float16* dst = (which == 0) ? qh : ((which == 1) ? kh : vh);
    const float scale = (which == 0) ? 0.125f : 1.0f;  // SCALE = 64^-0.5 folded into q
#pragma unroll
    for (int i = 0; i < 4; ++i) {
#pragma unroll
        for (int rr = 0; rr < 4; ++rr) {
            int grow = m0 + i * 16 + q * 4 + rr;
            int b_idx = grow / 197;
            int n_idx = grow - b_idx * 197;
            size_t rowoff = ((size_t)(b_idx * NH + hh) * NTOK + n_idx) * DH;
#pragma unroll
            for (int j = 0; j < 4; ++j) {
                int d0 = j * 16 + r;
                dst[rowoff + d0] = (_Float16)(acc[i][j][rr] * scale);
            }
        }
    }
}

// ---------------- attention: 1 block per (b,h), 4 waves, query tiles of 16 ----------------
__global__ __launch_bounds__(256) void attn_kernel(const _Float16* __restrict__ qh,
                                                   const _Float16* __restrict__ kh,
                                                   const _Float16* __restrict__ vh,
                                                   const float* __restrict__ biasp,
                                                   _Float16* __restrict__ ah) {
    __shared__ __align__(16) _Float16 Vt[64][232];      // V^T, padded cols zeroed  (29.0 KB)
    __shared__ __align__(16) _Float16 P[4][16][232];    // per-wave P tile          (29.0 KB)

    const int bh = blockIdx.x;
    const int b = bh / NH, h = bh - b * NH;
    const int tid = threadIdx.x;
    const int w = tid >> 6, lane = tid & 63;
    const int r = lane & 15, q = lane >> 4;
    const size_t base = (size_t)bh * NTOK * DH;
    const _Float16* Qb = qh + base;
    const _Float16* Kb = kh + base;
    const _Float16* Vb = vh + base;

    // stage V^T (coalesced read, one-time scatter write)
    for (int idx = tid; idx < KPAD * DH; idx += 256) {
        int j = idx >> 6, d = idx & 63;
        Vt[d][j] = (j < NTOK) ? Vb[(size_t)j * DH + d] : (_Float16)0.0f;
    }
    __syncthreads();

    for (int it = 0; it < 4; ++it) {
        int qt = it * 4 + w;
        bool active = qt < NKT;
        floatx4 oacc[4] = {};
        if (active) {
            // Q A-frags (reused across all key tiles)
            half8 aq0 = {}, aq1 = {};
            int rowq = qt * 16 + r;
            if (rowq < NTOK) {
                aq0 = *(const half8*)(Qb + (size_t)rowq * DH + q * 8);
                aq1 = *(const half8*)(Qb + (size_t)rowq * DH + 32 + q * 8);
            }
            // S = Q K^T  (13 key tiles x 2 MFMAs), acc in registers
            floatx4 sacc[NKT] = {};
#pragma unroll
            for (int nt = 0; nt < NKT; ++nt) {
                half8 b0 = {}, b1 = {};
                int rowk = nt * 16 + r;
                if (rowk < NTOK) {
                    b0 = *(const half8*)(Kb + (size_t)rowk * DH + q * 8);
                    b1 = *(const half8*)(Kb + (size_t)rowk * DH + 32 + q * 8);
                }
                sacc[nt] = MFMA16(aq0, b0, sacc[nt]);
                sacc[nt] = MFMA16(aq1, b1, sacc[nt]);
            }
            // bias + softmax per output row (row = q*4+rr lives in this quad's 16 lanes)
#pragma unroll
            for (int rr = 0; rr < 4; ++rr) {
                int irow = qt * 16 + q * 4 + rr;
                if (irow > NTOK - 1) irow = NTOK - 1;   // clamped; result discarded
                const float* bp = biasp + ((size_t)h * NTOK + irow) * KPAD + r;
                float sv[NKT];
                float mx = -3.0e38f;
#pragma unroll
                for (int nt = 0; nt < NKT; ++nt) {
                    float s = sacc[nt][rr] + bp[nt * 16];   // pad cols carry -1e30
                    sv[nt] = s;
                    mx = fmaxf(mx, s);
                }
#pragma unroll
                for (int msk = 1; msk <= 8; msk <<= 1) mx = fmaxf(mx, __shfl_xor(mx, msk, 64));
                float sum = 0.f;
#pragma unroll
                for (int nt = 0; nt < NKT; ++nt) {
                    float e = __expf(sv[nt] - mx);
                    sv[nt] = e;
                    sum += e;
                }
#pragma unroll
                for (int msk = 1; msk <= 8; msk <<= 1) sum += __shfl_xor(sum, msk, 64);
                float inv = 1.0f / sum;
                int prow = q * 4 + rr;
#pragma unroll
                for (int nt = 0; nt < NKT; ++nt)
                    P[w][prow][nt * 16 + r] = (_Float16)(sv[nt] * inv);
                P[w][prow][208 + r] = (_Float16)0.0f;   // zero cols 208..223
            }
        }
        __syncthreads();   // intra-wave LDS ordering + uniform across waves
        if (active) {
            // O = P V : A-frags from P (LDS), B-frags from V^T (LDS)
#pragma unroll
            for (int kt = 0; kt < 7; ++kt) {
                half8 ap = *(const half8*)&P[w][r][kt * 32 + q * 8];
#pragma unroll
                for (int dt = 0; dt < 4; ++dt) {
                    half8 bv = *(const half8*)&Vt[dt * 16 + r][kt * 32 + q * 8];
                    oacc[dt] = MFMA16(ap, bv, oacc[dt]);
                }
            }
#pragma unroll
            for (int rr = 0; rr < 4; ++rr) {
                int rowq = qt * 16 + q * 4 + rr;
                if (rowq < NTOK) {
                    size_t o = ((size_t)b * NTOK + rowq) * DIM + h * DH;
#pragma unroll
                    for (int dt = 0; dt < 4; ++dt)
                        ah[o + dt * 16 + r] = (_Float16)oacc[dt][rr];
                }
            }
        }
        __syncthreads();
    }
}

// ---------------- proj GEMM: [25216,768] x [768,768]^T + bias -> fp32 out ----------------
__global__ __launch_bounds__(256) void proj_gemm(const _Float16* __restrict__ A,
                                                 const _Float16* __restrict__ W,
                                                 const float* __restrict__ bias,
                                                 float* __restrict__ out) {
    const int lane = threadIdx.x & 63;
    const int w = threadIdx.x >> 6;
    const int r = lane & 15, q = lane >> 4;
    const int m0 = blockIdx.y * 128 + (w & 1) * 64;
    const int n0 = blockIdx.x * 128 + (w >> 1) * 64;

    floatx4 acc[4][4] = {};
    const half8* pa[4];
    const half8* pb[4];
#pragma unroll
    for (int i = 0; i < 4; ++i)
        pa[i] = (const half8*)A + ((size_t)(m0 + i * 16 + r) * 96 + q);
#pragma unroll
    for (int j = 0; j < 4; ++j)
        pb[j] = (const half8*)W + ((size_t)(n0 + j * 16 + r) * 96 + q);

    for (int kk = 0; kk < 24; ++kk) {
        half8 a[4], b[4];
#pragma unroll
        for (int i = 0; i < 4; ++i) a[i] = pa[i][kk * 4];
#pragma unroll
        for (int j = 0; j < 4; ++j) b[j] = pb[j][kk * 4];
#pragma unroll
        for (int i = 0; i < 4; ++i)
#pragma unroll
            for (int j = 0; j < 4; ++j)
                acc[i][j] = MFMA16(a[i], b[j], acc[i][j]);
    }
#pragma unroll
    for (int i = 0; i < 4; ++i) {
#pragma unroll
        for (int rr = 0; rr < 4; ++rr) {
            size_t grow = m0 + i * 16 + q * 4 + rr;
#pragma unroll
            for (int j = 0; j < 4; ++j) {
                int gcol = n0 + j * 16 + r;
                out[grow * DIM + gcol] = acc[i][j][rr] + bias[gcol];
            }
        }
    }
}

// ---------------- launch ----------------
extern "C" void kernel_launch(void* const* d_in, const int* in_sizes, int n_in,
                              void* d_out, int out_size, void* d_ws, size_t ws_size,
                              hipStream_t stream) {
    const float* x = (const float*)d_in[0];        // [128,197,768]
    const float* qkv_w = (const float*)d_in[1];    // [2304,768]
    const float* proj_w = (const float*)d_in[2];   // [768,768]
    const float* proj_b = (const float*)d_in[3];   // [768]
    const float* table = (const float*)d_in[4];    // [730,12]
    const int* ridx = (const int*)d_in[5];         // [197,197]
    float* out = (float*)d_out;

    char* ws = (char*)d_ws;
    const size_t SZ_X = (size_t)M_ROWS * DIM * 2;        // 38,731,776 (f16)
    const size_t SZ_WQKV = (size_t)3 * DIM * DIM * 2;    //  3,538,944
    const size_t SZ_WPROJ = (size_t)DIM * DIM * 2;       //  1,179,648
    const size_t SZ_HEAD = (size_t)BATCH * NH * NTOK * DH * 2;  // 38,731,776
    const size_t SZ_BIAS = (size_t)NH * NTOK * KPAD * 4; //  2,118,144

    _Float16* xh = (_Float16*)(ws + 0);
    _Float16* ah = (_Float16*)(ws + 0);              // aliases xh (x dead after qkv gemm)
    _Float16* wqkvh = (_Float16*)(ws + SZ_X);
    _Float16* wprojh = (_Float16*)(ws + SZ_X + SZ_WQKV);
    _Float16* qh = (_Float16*)(ws + SZ_X + SZ_WQKV + SZ_WPROJ);
    _Float16* kh = (_Float16*)(ws + SZ_X + SZ_WQKV + SZ_WPROJ + SZ_HEAD);
    _Float16* vh = (_Float16*)(ws + SZ_X + SZ_WQKV + SZ_WPROJ + 2 * SZ_HEAD);
    float* biasp = (float*)(ws + SZ_X + SZ_WQKV + SZ_WPROJ + 3 * SZ_HEAD);
    (void)SZ_BIAS; (void)ws_size; (void)n_in; (void)in_sizes; (void)out_size;

    // converts
    {
        int n4 = M_ROWS * DIM / 4;
        cvt_f32_f16<<<(n4 + 255) / 256, 256, 0, stream>>>(x, xh, n4);
        n4 = 3 * DIM * DIM / 4;
        cvt_f32_f16<<<(n4 + 255) / 256, 256, 0, stream>>>(qkv_w, wqkvh, n4);
        n4 = DIM * DIM / 4;
        cvt_f32_f16<<<(n4 + 255) / 256, 256, 0, stream>>>(proj_w, wprojh, n4);
    }
    // bias precompute
    {
        int n = NH * NTOK * KPAD;
        bias_pre<<<(n + 255) / 256, 256, 0, stream>>>(table, ridx, biasp);
    }
    // qkv gemm
    {
        dim3 grid(3 * DIM / 128, M_ROWS / 128);  // (18, 197)
        qkv_gemm<<<grid, 256, 0, stream>>>(xh, wqkvh, qh, kh, vh);
    }
    // attention
    attn_kernel<<<BATCH * NH, 256, 0, stream>>>(qh, kh, vh, biasp, ah);
    // proj gemm
    {
        dim3 grid(DIM / 128, M_ROWS / 128);      // (6, 197)
        proj_gemm<<<grid, 256, 0, stream>>>(ah, wprojh, proj_b, out);
    }
}

// Round 2
// 460.029 us; speedup vs baseline: 1.6023x; 1.6023x over previous
//
#include <hip/hip_runtime.h>
#include <hip/hip_bf16.h>

// ---------------- types ----------------
typedef _Float16 half8 __attribute__((ext_vector_type(8)));
typedef _Float16 half4 __attribute__((ext_vector_type(4)));
typedef float floatx4 __attribute__((ext_vector_type(4)));

#define MFMA16(a, b, c) __builtin_amdgcn_mfma_f32_16x16x32_f16(a, b, c, 0, 0, 0)
#define GLDS16(gp, lp) __builtin_amdgcn_global_load_lds( \
    (const __attribute__((address_space(1))) void*)(gp), \
    (__attribute__((address_space(3))) void*)(lp), 16, 0, 0)

// Problem constants
#define BATCH 128
#define NTOK 197
#define DIM 768
#define NH 12
#define DH 64
#define TABLE 730
#define M_ROWS (BATCH * NTOK)       // 25216 = 197 * 128
#define KPAD 224                    // padded key count for PV (7 * 32)
#define NKT 13                      // key tiles of 16 for S (13*16 = 208 >= 197)

// ---------------- fp32 -> fp16 convert ----------------
__global__ void cvt_f32_f16(const float* __restrict__ src, _Float16* __restrict__ dst, int n4) {
    int i = blockIdx.x * 256 + threadIdx.x;
    if (i < n4) {
        float4 v = ((const float4*)src)[i];
        half4 o;
        o[0] = (_Float16)v.x; o[1] = (_Float16)v.y;
        o[2] = (_Float16)v.z; o[3] = (_Float16)v.w;
        ((half4*)dst)[i] = o;
    }
}

// ---------------- bias precompute: [12][197][224], pad cols = -1e30 ----------------
__global__ void bias_pre(const float* __restrict__ table, const int* __restrict__ ridx,
                         float* __restrict__ biasp) {
    int idx = blockIdx.x * 256 + threadIdx.x;
    if (idx >= NH * NTOK * KPAD) return;
    int h = idx / (NTOK * KPAD);
    int rem = idx - h * (NTOK * KPAD);
    int i = rem / KPAD;
    int j = rem - i * KPAD;
    float v = -1.0e30f;
    if (j < NTOK) v = table[ridx[i * NTOK + j] * NH + h];
    biasp[idx] = v;
}

// =====================================================================
// m97-style GEMM core: 128x128 block tile, BK=64, LDS staged via
// global_load_lds (16B/lane), XOR-swizzled atom layout so ds_read_b128
// fragment reads are bank-conflict-free.
//
// LDS layout: tile[row][atomcol], atomcol 0..7 (16B atoms). Slot
// (row, atomcol) holds global k-atom (atomcol ^ (row&7)) of row `row`.
// Staging chunk = 8 rows = 1024B = one global_load_lds per wave;
// wave w stages rows [w*32, w*32+32) of both A and B (4 chunks each).
// Fragment read: k-atom (s*4+q) of row `row` is at atomcol
// ((s*4+q) ^ (row&7)) -> uniform 8 dword-accesses per bank (free).
//
// Wave w computes the 64x64 sub-tile at (mo=(w&1)*64, no=(w>>1)*64):
// A-frag rows mo+i*16+r, B-frag rows no+j*16+r.
// =====================================================================
__device__ __forceinline__ void gemm_core_768(const _Float16* __restrict__ A,
                                              const _Float16* __restrict__ B,
                                              int m0b, int n0b,
                                              _Float16* As, _Float16* Bs,
                                              floatx4 acc[4][4]) {
    const int lane = threadIdx.x & 63;
    const int w = threadIdx.x >> 6;
    const int r = lane & 15, q = lane >> 4;
    const int mo = (w & 1) * 64;                    // wave sub-tile row offset in A
    const int no = (w >> 1) * 64;                   // wave sub-tile row offset in B
    const int srow = w * 32 + (lane >> 3);          // staging row (per chunk +8)
    const int gatom = (lane & 7) ^ (lane >> 3);     // swizzled k-atom this lane fetches
    const int rx = r & 7;                           // row&7 for this lane's frag rows

    const _Float16* pa[4];
    const _Float16* pb[4];
#pragma unroll
    for (int c = 0; c < 4; ++c) {
        pa[c] = A + (size_t)(m0b + srow + c * 8) * DIM + gatom * 8;
        pb[c] = B + (size_t)(n0b + srow + c * 8) * DIM + gatom * 8;
    }
    _Float16* ldsA = As + w * 2048;                 // w*4 chunks * 512 f16
    _Float16* ldsB = Bs + w * 2048;

    for (int kk = 0; kk < DIM / 64; ++kk) {
#pragma unroll
        for (int c = 0; c < 4; ++c) {
            GLDS16(pa[c], ldsA + c * 512);
            GLDS16(pb[c], ldsB + c * 512);
            pa[c] += 64;
            pb[c] += 64;
        }
        __syncthreads();   // vmcnt(0) drain + barrier: staged tile visible
#pragma unroll
        for (int s = 0; s < 2; ++s) {
            half8 a[4], b[4];
#pragma unroll
            for (int i = 0; i < 4; ++i)
                a[i] = *(const half8*)&As[((mo + i * 16 + r) * 8 + ((s * 4 + q) ^ rx)) * 8];
#pragma unroll
            for (int j = 0; j < 4; ++j)
                b[j] = *(const half8*)&Bs[((no + j * 16 + r) * 8 + ((s * 4 + q) ^ rx)) * 8];
#pragma unroll
            for (int i = 0; i < 4; ++i)
#pragma unroll
                for (int j = 0; j < 4; ++j)
                    acc[i][j] = MFMA16(a[i], b[j], acc[i][j]);
        }
        __syncthreads();   // all waves done reading before next stage
    }
}

// ---------------- QKV GEMM: [25216,768] x [2304,768]^T -> scatter q/k/v [B,H,N,64] ----
__global__ __launch_bounds__(256) void qkv_gemm(const _Float16* __restrict__ X,
                                                const _Float16* __restrict__ W,
                                                _Float16* __restrict__ qh,
                                                _Float16* __restrict__ kh,
                                                _Float16* __restrict__ vh) {
    __shared__ __align__(16) _Float16 As[128 * 64];
    __shared__ __align__(16) _Float16 Bs[128 * 64];
    const int lane = threadIdx.x & 63;
    const int w = threadIdx.x >> 6;
    const int r = lane & 15, q = lane >> 4;

    floatx4 acc[4][4] = {};
    gemm_core_768(X, W, blockIdx.y * 128, blockIdx.x * 128, As, Bs, acc);

    const int m0 = blockIdx.y * 128 + (w & 1) * 64;
    const int n0 = blockIdx.x * 128 + (w >> 1) * 64;
    // n0 is a multiple of 64; a 64-col block never crosses the 768 boundary
    const int which = n0 / 768;              // 0=q 1=k 2=v (uniform per wave)
    const int hh = (n0 % 768) / 64;
    _Float16* dst = (which == 0) ? qh : ((which == 1) ? kh : vh);
    const float scale = (which == 0) ? 0.125f : 1.0f;  // SCALE = 64^-0.5 folded into q
#pragma unroll
    for (int i = 0; i < 4; ++i) {
#pragma unroll
        for (int rr = 0; rr < 4; ++rr) {
            int grow = m0 + i * 16 + q * 4 + rr;
            int b_idx = grow / 197;
            int n_idx = grow - b_idx * 197;
            size_t rowoff = ((size_t)(b_idx * NH + hh) * NTOK + n_idx) * DH;
#pragma unroll
            for (int j = 0; j < 4; ++j) {
                int d0 = j * 16 + r;
                dst[rowoff + d0] = (_Float16)(acc[i][j][rr] * scale);
            }
        }
    }
}

// ---------------- proj GEMM: [25216,768] x [768,768]^T + bias -> fp32 out ----------------
__global__ __launch_bounds__(256) void proj_gemm(const _Float16* __restrict__ A,
                                                 const _Float16* __restrict__ W,
                                                 const float* __restrict__ bias,
                                                 float* __restrict__ out) {
    __shared__ __align__(16) _Float16 As[128 * 64];
    __shared__ __align__(16) _Float16 Bs[128 * 64];
    const int lane = threadIdx.x & 63;
    const int w = threadIdx.x >> 6;
    const int r = lane & 15, q = lane >> 4;

    floatx4 acc[4][4] = {};
    gemm_core_768(A, W, blockIdx.y * 128, blockIdx.x * 128, As, Bs, acc);

    const int m0 = blockIdx.y * 128 + (w & 1) * 64;
    const int n0 = blockIdx.x * 128 + (w >> 1) * 64;
#pragma unroll
    for (int i = 0; i < 4; ++i) {
#pragma unroll
        for (int rr = 0; rr < 4; ++rr) {
            size_t grow = m0 + i * 16 + q * 4 + rr;
#pragma unroll
            for (int j = 0; j < 4; ++j) {
                int gcol = n0 + j * 16 + r;
                out[grow * DIM + gcol] = acc[i][j][rr] + bias[gcol];
            }
        }
    }
}

// ---------------- attention: 1 block per (b,h), 4 waves, query tiles of 16 ----------------
__global__ __launch_bounds__(256) void attn_kernel(const _Float16* __restrict__ qh,
                                                   const _Float16* __restrict__ kh,
                                                   const _Float16* __restrict__ vh,
                                                   const float* __restrict__ biasp,
                                                   _Float16* __restrict__ ah) {
    __shared__ __align__(16) _Float16 Vt[64][232];      // V^T, padded cols zeroed  (29.0 KB)
    __shared__ __align__(16) _Float16 P[4][16][232];    // per-wave P tile          (29.0 KB)

    const int bh = blockIdx.x;
    const int b = bh / NH, h = bh - b * NH;
    const int tid = threadIdx.x;
    const int w = tid >> 6, lane = tid & 63;
    const int r = lane & 15, q = lane >> 4;
    const size_t base = (size_t)bh * NTOK * DH;
    const _Float16* Qb = qh + base;
    const _Float16* Kb = kh + base;
    const _Float16* Vb = vh + base;

    // stage V^T (coalesced read, one-time scatter write)
    for (int idx = tid; idx < KPAD * DH; idx += 256) {
        int j = idx >> 6, d = idx & 63;
        Vt[d][j] = (j < NTOK) ? Vb[(size_t)j * DH + d] : (_Float16)0.0f;
    }
    __syncthreads();

    for (int it = 0; it < 4; ++it) {
        int qt = it * 4 + w;
        bool active = qt < NKT;
        floatx4 oacc[4] = {};
        if (active) {
            // Q A-frags (reused across all key tiles)
            half8 aq0 = {}, aq1 = {};
            int rowq = qt * 16 + r;
            if (rowq < NTOK) {
                aq0 = *(const half8*)(Qb + (size_t)rowq * DH + q * 8);
                aq1 = *(const half8*)(Qb + (size_t)rowq * DH + 32 + q * 8);
            }
            // S = Q K^T  (13 key tiles x 2 MFMAs), acc in registers
            floatx4 sacc[NKT] = {};
#pragma unroll
            for (int nt = 0; nt < NKT; ++nt) {
                half8 b0 = {}, b1 = {};
                int rowk = nt * 16 + r;
                if (rowk < NTOK) {
                    b0 = *(const half8*)(Kb + (size_t)rowk * DH + q * 8);
                    b1 = *(const half8*)(Kb + (size_t)rowk * DH + 32 + q * 8);
                }
                sacc[nt] = MFMA16(aq0, b0, sacc[nt]);
                sacc[nt] = MFMA16(aq1, b1, sacc[nt]);
            }
            // bias + softmax per output row (row = q*4+rr lives in this quad's 16 lanes)
#pragma unroll
            for (int rr = 0; rr < 4; ++rr) {
                int irow = qt * 16 + q * 4 + rr;
                if (irow > NTOK - 1) irow = NTOK - 1;   // clamped; result discarded
                const float* bp = biasp + ((size_t)h * NTOK + irow) * KPAD + r;
                float sv[NKT];
                float mx = -3.0e38f;
#pragma unroll
                for (int nt = 0; nt < NKT; ++nt) {
                    float s = sacc[nt][rr] + bp[nt * 16];   // pad cols carry -1e30
                    sv[nt] = s;
                    mx = fmaxf(mx, s);
                }
#pragma unroll
                for (int msk = 1; msk <= 8; msk <<= 1) mx = fmaxf(mx, __shfl_xor(mx, msk, 64));
                float sum = 0.f;
#pragma unroll
                for (int nt = 0; nt < NKT; ++nt) {
                    float e = __expf(sv[nt] - mx);
                    sv[nt] = e;
                    sum += e;
                }
#pragma unroll
                for (int msk = 1; msk <= 8; msk <<= 1) sum += __shfl_xor(sum, msk, 64);
                float inv = 1.0f / sum;
                int prow = q * 4 + rr;
#pragma unroll
                for (int nt = 0; nt < NKT; ++nt)
                    P[w][prow][nt * 16 + r] = (_Float16)(sv[nt] * inv);
                P[w][prow][208 + r] = (_Float16)0.0f;   // zero cols 208..223
            }
        }
        __syncthreads();   // intra-wave LDS ordering + uniform across waves
        if (active) {
            // O = P V : A-frags from P (LDS), B-frags from V^T (LDS)
#pragma unroll
            for (int kt = 0; kt < 7; ++kt) {
                half8 ap = *(const half8*)&P[w][r][kt * 32 + q * 8];
#pragma unroll
                for (int dt = 0; dt < 4; ++dt) {
                    half8 bv = *(const half8*)&Vt[dt * 16 + r][kt * 32 + q * 8];
                    oacc[dt] = MFMA16(ap, bv, oacc[dt]);
                }
            }
#pragma unroll
            for (int rr = 0; rr < 4; ++rr) {
                int rowq = qt * 16 + q * 4 + rr;
                if (rowq < NTOK) {
                    size_t o = ((size_t)b * NTOK + rowq) * DIM + h * DH;
#pragma unroll
                    for (int dt = 0; dt < 4; ++dt)
                        ah[o + dt * 16 + r] = (_Float16)oacc[dt][rr];
                }
            }
        }
        __syncthreads();
    }
}

// ---------------- launch ----------------
extern "C" void kernel_launch(void* const* d_in, const int* in_sizes, int n_in,
                              void* d_out, int out_size, void* d_ws, size_t ws_size,
                              hipStream_t stream) {
    const float* x = (const float*)d_in[0];        // [128,197,768]
    const float* qkv_w = (const float*)d_in[1];    // [2304,768]
    const float* proj_w = (const float*)d_in[2];   // [768,768]
    const float* proj_b = (const float*)d_in[3];   // [768]
    const float* table = (const float*)d_in[4];    // [730,12]
    const int* ridx = (const int*)d_in[5];         // [197,197]
    float* out = (float*)d_out;

    char* ws = (char*)d_ws;
    const size_t SZ_X = (size_t)M_ROWS * DIM * 2;        // 38,731,776 (f16)
    const size_t SZ_WQKV = (size_t)3 * DIM * DIM * 2;    //  3,538,944
    const size_t SZ_WPROJ = (size_t)DIM * DIM * 2;       //  1,179,648
    const size_t SZ_HEAD = (size_t)BATCH * NH * NTOK * DH * 2;  // 38,731,776
    const size_t SZ_BIAS = (size_t)NH * NTOK * KPAD * 4; //  2,118,144

    _Float16* xh = (_Float16*)(ws + 0);
    _Float16* ah = (_Float16*)(ws + 0);              // aliases xh (x dead after qkv gemm)
    _Float16* wqkvh = (_Float16*)(ws + SZ_X);
    _Float16* wprojh = (_Float16*)(ws + SZ_X + SZ_WQKV);
    _Float16* qh = (_Float16*)(ws + SZ_X + SZ_WQKV + SZ_WPROJ);
    _Float16* kh = (_Float16*)(ws + SZ_X + SZ_WQKV + SZ_WPROJ + SZ_HEAD);
    _Float16* vh = (_Float16*)(ws + SZ_X + SZ_WQKV + SZ_WPROJ + 2 * SZ_HEAD);
    float* biasp = (float*)(ws + SZ_X + SZ_WQKV + SZ_WPROJ + 3 * SZ_HEAD);
    (void)SZ_BIAS; (void)ws_size; (void)n_in; (void)in_sizes; (void)out_size;

    // converts
    {
        int n4 = M_ROWS * DIM / 4;
        cvt_f32_f16<<<(n4 + 255) / 256, 256, 0, stream>>>(x, xh, n4);
        n4 = 3 * DIM * DIM / 4;
        cvt_f32_f16<<<(n4 + 255) / 256, 256, 0, stream>>>(qkv_w, wqkvh, n4);
        n4 = DIM * DIM / 4;
        cvt_f32_f16<<<(n4 + 255) / 256, 256, 0, stream>>>(proj_w, wprojh, n4);
    }
    // bias precompute
    {
        int n = NH * NTOK * KPAD;
        bias_pre<<<(n + 255) / 256, 256, 0, stream>>>(table, ridx, biasp);
    }
    // qkv gemm
    {
        dim3 grid(3 * DIM / 128, M_ROWS / 128);  // (18, 197)
        qkv_gemm<<<grid, 256, 0, stream>>>(xh, wqkvh, qh, kh, vh);
    }
    // attention
    attn_kernel<<<BATCH * NH, 256, 0, stream>>>(qh, kh, vh, biasp, ah);
    // proj gemm
    {
        dim3 grid(DIM / 128, M_ROWS / 128);      // (6, 197)
        proj_gemm<<<grid, 256, 0, stream>>>(ah, wprojh, proj_b, out);
    }
}